// Round 10
// baseline (334.913 us; speedup 1.0000x reference)
//
#include <hip/hip_runtime.h>
#include <math.h>

// Problem constants (from reference setup_inputs): B=16, A=16384, C=81, TOP_K=64
constexpr int B_N  = 16;
constexpr int A_N  = 16384;
constexpr int C_N  = 81;
constexpr int TOPK = 64;
constexpr int DNT  = 256;            // decode kernel block size
constexpr int NBINS = 232;           // score-bit bins covering (0.3, 1.0)
constexpr int CAP   = 512;           // candidate band capacity (pow2, 8/lane)
constexpr unsigned BIN_BASE = 0x3E99u;   // __float_as_uint(0.3f) >> 16

// sigmoid+transpose tile: 64 anchors x 81 classes per block (round-9 v3).
constexpr int TA   = 64;
constexpr int TPAD = 85;
constexpr int TNT  = 256;
constexpr int TILE_ELEMS = TA * C_N;       // 5184
constexpr int TILE_F4    = (TA / 4) * C_N; // 1296 float4 stores per tile

constexpr int SNT = 256;             // fused select+nms block size
constexpr int RPT = A_N / 4 / SNT;   // 16 float4 per thread (register-resident)

// ---------------------------------------------------------------------------
// Kernel 1: SSD box decode (unchanged — bit-exact vs ref across rounds 1-9).
// ---------------------------------------------------------------------------
__global__ __launch_bounds__(DNT) void decode_kernel(const float4* __restrict__ loc,
                                                     const float4* __restrict__ anch,
                                                     float4* __restrict__ boxes) {
    int i = blockIdx.x * DNT + threadIdx.x;
    int a = i & (A_N - 1);
    float4 l  = loc[i];
    float4 an = anch[a];
    float cx = an.x + (l.x * 0.1f) * an.z;
    float cy = an.y + (l.y * 0.1f) * an.w;
    float w  = an.z * expf(l.z * 0.2f);
    float h  = an.w * expf(l.w * 0.2f);
    float x1 = cx - w * 0.5f;
    float y1 = cy - h * 0.5f;
    boxes[i] = make_float4(x1, y1, x1 + w, y1 + h);
}

// ---------------------------------------------------------------------------
// Kernel 1b: fused sigmoid + transpose (unchanged from round 9).
// ---------------------------------------------------------------------------
__global__ __launch_bounds__(TNT) void sigT_kernel(const float* __restrict__ conf,
                                                   float* __restrict__ scoresT) {
    __shared__ float tile[TA][TPAD];

    const int a0 = blockIdx.x * TA;
    const int b  = blockIdx.y;
    const int t  = threadIdx.x;

    const float* src = conf + ((size_t)b * A_N + a0) * C_N;
#pragma unroll
    for (int i = 0; i < (TILE_ELEMS + TNT - 1) / TNT; ++i) {
        int idx = i * TNT + t;
        if (idx < TILE_ELEMS) {
            float x  = src[idx];                   // fully coalesced
            int   al = idx / C_N;
            int   cc = idx - al * C_N;
            tile[al][cc] = 1.0f / (1.0f + expf(-x));
        }
    }
    __syncthreads();
    float* dst = scoresT + (size_t)b * C_N * A_N + a0;
#pragma unroll
    for (int i = 0; i < (TILE_F4 + TNT - 1) / TNT; ++i) {
        int idx4 = i * TNT + t;
        if (idx4 < TILE_F4) {
            int cc  = idx4 >> 4;                   // 16 float4 per class row
            int al4 = idx4 & 15;
            float4 v;
            v.x = tile[al4 * 4 + 0][cc];
            v.y = tile[al4 * 4 + 1][cc];
            v.z = tile[al4 * 4 + 2][cc];
            v.w = tile[al4 * 4 + 3][cc];
            ((float4*)(dst + (size_t)cc * A_N))[al4] = v;   // dwordx4 stores
        }
    }
}

// ---------------------------------------------------------------------------
// Kernel 2: FUSED select + NMS, v2 — one 256-thread block per (b,c).
// Round-10 change: SINGLE PASS over scoresT. All 16 float4 loads are issued
// up-front into registers (16 outstanding loads/wave -> BW-bound streaming,
// not latency-bound), histogram and band compaction (incl. refills) then run
// from registers — the round-9 second 64 KB read + re-classify is gone.
// Selection semantics verbatim from passing rounds 4-9: same bin formula,
// band walk with refill + clamp, key=(score_bits<<32)|~idx (unique keys =>
// sorted order independent of compaction arrival order), same wave bitonic,
// same IoU operand order, same accept/output logic.
// ---------------------------------------------------------------------------
__global__ __launch_bounds__(SNT, 4) void select_nms_kernel(
        const float* __restrict__ scoresT,
        const float4* __restrict__ boxes,
        float* __restrict__ out) {
    __shared__ int hist[NBINS];
    __shared__ unsigned long long cand[CAP];
    __shared__ float4 cbox[CAP];
    __shared__ int s_cnt, s_acc, s_kout;

    const int bc   = blockIdx.x;           // b*C_N + c
    const int b    = bc / C_N;
    const int t    = threadIdx.x;
    const int lane = t & 63;
    const int wv   = t >> 6;

    for (int i = t; i < NBINS; i += SNT) hist[i] = 0;
    if (t == 0) { s_acc = 0; s_kout = 0; }
    __syncthreads();

    const float4* sptr = (const float4*)(scoresT + (size_t)bc * A_N);
    const float4* bptr = boxes + (size_t)b * A_N;
    float* optr = out + (size_t)bc * TOPK * 5;

    // --- issue ALL row loads up-front (16 outstanding/wave), keep in regs ---
    float4 sv[RPT];
#pragma unroll
    for (int i = 0; i < RPT; ++i) sv[i] = sptr[t + SNT * i];

    // --- pass 1: histogram from registers ---
#pragma unroll
    for (int i = 0; i < RPT; ++i) {
        float s[4] = {sv[i].x, sv[i].y, sv[i].z, sv[i].w};
#pragma unroll
        for (int q = 0; q < 4; ++q) {
            if (s[q] > 0.3f) {
                unsigned u = __float_as_uint(s[q]);
                int bin = (int)(u >> 16) - (int)BIN_BASE;
                bin = bin < 0 ? 0 : (bin > NBINS - 1 ? NBINS - 1 : bin);
                atomicAdd(&hist[bin], 1);
            }
        }
    }
    __syncthreads();

    // Accepted boxes: one per lane of wave 0, in registers.
    float rx1 = 0.f, ry1 = 0.f, rx2 = 0.f, ry2 = 0.f, rar = 0.f;
    int acc = 0, kout = 0;                 // live on wave 0; mirrored via s_acc

    int bin_hi = NBINS;
    for (;;) {
        // --- band walk (redundant on all threads; wave-uniform LDS reads) ---
        int lo = bin_hi, tot = 0;
        while (lo > 0) {
            int cnt = hist[lo - 1];
            if (tot + cnt > CAP) {
                if (tot == 0) { lo--; }            // single bin > CAP: take it (clamped)
                break;
            }
            tot += cnt; lo--;
        }
        const int bin_lo = lo;
        if (bin_lo == bin_hi) break;               // all bins consumed -> exhausted
        if (t == 0) s_cnt = 0;
        __syncthreads();

        // --- compact this band into LDS, FROM REGISTERS (no global re-read) ---
#pragma unroll
        for (int i = 0; i < RPT; ++i) {
            float s[4] = {sv[i].x, sv[i].y, sv[i].z, sv[i].w};
#pragma unroll
            for (int q = 0; q < 4; ++q) {
                if (s[q] > 0.3f) {
                    unsigned u = __float_as_uint(s[q]);
                    int bin = (int)(u >> 16) - (int)BIN_BASE;
                    bin = bin < 0 ? 0 : (bin > NBINS - 1 ? NBINS - 1 : bin);
                    if (bin >= bin_lo && bin < bin_hi) {
                        int slot = atomicAdd(&s_cnt, 1);
                        if (slot < CAP) {
                            unsigned a = (unsigned)(4 * (t + SNT * i) + q);
                            cand[slot] = ((unsigned long long)u << 32) | (unsigned)(~a);
                        }
                    }
                }
            }
        }
        __syncthreads();
        int C = s_cnt; if (C > CAP) C = CAP;       // uniform across block

        if (C > 0) {
            // --- wave-0 register bitonic sort (no barriers needed in-wave) ---
            if (wv == 0) {
                unsigned long long key[8];
#pragma unroll
                for (int r = 0; r < 8; ++r) {
                    int sidx = r * 64 + lane;
                    key[r] = (sidx < C) ? cand[sidx] : 0ull;   // pad: 0 < any real key
                }
#pragma unroll
                for (int k = 2; k <= CAP; k <<= 1) {
#pragma unroll
                    for (int j = k >> 1; j > 0; j >>= 1) {
                        if (j >= 64) {
                            int jr = j >> 6;               // 1,2,4: in-lane pairs
#pragma unroll
                            for (int r = 0; r < 8; ++r) {
                                int rp = r ^ jr;
                                if (rp > r) {
                                    int e = r * 64 + lane;
                                    bool up = ((e & k) == 0);
                                    unsigned long long va = key[r], vb = key[rp];
                                    bool sw = up ? (va < vb) : (va > vb);
                                    if (sw) { key[r] = vb; key[rp] = va; }
                                }
                            }
                        } else {                            // cross-lane via shfl
#pragma unroll
                            for (int r = 0; r < 8; ++r) {
                                int e = r * 64 + lane;
                                bool up    = ((e & k) == 0);
                                bool isLow = ((lane & j) == 0);
                                unsigned long long va = key[r];
                                unsigned long long vb = __shfl_xor(va, j, 64);
                                bool keepMax = (up == isLow);
                                key[r] = keepMax ? (va > vb ? va : vb)
                                                 : (va < vb ? va : vb);
                            }
                        }
                    }
                }
#pragma unroll
                for (int r = 0; r < 8; ++r) cand[r * 64 + lane] = key[r];
            }
            __syncthreads();

            // --- gather candidate boxes into LDS (256 threads, 2 each) ---
            for (int e = t; e < CAP; e += SNT)
                if (e < C) cbox[e] = bptr[(int)(~(unsigned)cand[e])];
            __syncthreads();

            // --- ordered greedy scan on wave 0 (1-deep prefetch from LDS) ---
            if (wv == 0) {
                int ts = 0;
                unsigned long long k0 = cand[0];
                float4 cb = cbox[0];
                while (ts < C) {
                    unsigned long long nk = 0ull;
                    float4 nb = cb;
                    if (ts + 1 < C) { nk = cand[ts + 1]; nb = cbox[ts + 1]; }
                    float sc = __uint_as_float((unsigned)(k0 >> 32));
                    float ca = (cb.z - cb.x) * (cb.w - cb.y);
                    bool over = false;
                    if (lane < acc) {
                        float tlx = fmaxf(rx1, cb.x);
                        float tly = fmaxf(ry1, cb.y);
                        float brx = fminf(rx2, cb.z);
                        float bry = fminf(ry2, cb.w);
                        float iw  = fmaxf(brx - tlx, 0.0f);
                        float ih  = fmaxf(bry - tly, 0.0f);
                        float inter = iw * ih;
                        float iou = inter / (rar + ca - inter); // ref operand order
                        over = iou > 0.5f;
                    }
                    if (!__any(over)) {
                        if (lane == acc) { rx1 = cb.x; ry1 = cb.y; rx2 = cb.z; ry2 = cb.w; rar = ca; }
                        if (lane == 0) {
                            float* o = optr + (size_t)kout * 5;
                            o[0] = sc; o[1] = cb.x; o[2] = cb.y; o[3] = cb.z; o[4] = cb.w;
                        }
                        acc++; kout++;                      // wave-uniform
                        if (acc == TOPK) break;
                    }
                    ++ts; k0 = nk; cb = nb;
                }
                if (lane == 0) { s_acc = acc; s_kout = kout; }
            }
            __syncthreads();
            if (s_acc >= TOPK) break;                      // uniform
        }
        bin_hi = bin_lo;
    }

    // Zero-fill remaining rows (harness poisons d_out with 0xAA every launch).
    {
        const int ko = s_kout;                             // uniform (post-barrier)
        float* o  = optr + (size_t)ko * 5;
        int   rem = (TOPK - ko) * 5;
        for (int i = t; i < rem; i += SNT) o[i] = 0.0f;
    }
}

// ---------------------------------------------------------------------------
// Fallback: standalone one-wave NMS reading strided conf (proven r6-9 path),
// used only if d_ws is too small for scoresT.
// ---------------------------------------------------------------------------
__device__ __forceinline__ void sort_gather_scan64(
        unsigned long long* cand, float4* cbox, int C, int lane,
        const float4* __restrict__ bptr, float* __restrict__ optr,
        float& rx1, float& ry1, float& rx2, float& ry2, float& rar,
        int& acc, int& kout) {
    unsigned long long key[8];
#pragma unroll
    for (int r = 0; r < 8; ++r) {
        int sidx = r * 64 + lane;
        key[r] = (sidx < C) ? cand[sidx] : 0ull;
    }
#pragma unroll
    for (int k = 2; k <= CAP; k <<= 1) {
#pragma unroll
        for (int j = k >> 1; j > 0; j >>= 1) {
            if (j >= 64) {
                int jr = j >> 6;
#pragma unroll
                for (int r = 0; r < 8; ++r) {
                    int rp = r ^ jr;
                    if (rp > r) {
                        int e = r * 64 + lane;
                        bool up = ((e & k) == 0);
                        unsigned long long va = key[r], vb = key[rp];
                        bool sw = up ? (va < vb) : (va > vb);
                        if (sw) { key[r] = vb; key[rp] = va; }
                    }
                }
            } else {
#pragma unroll
                for (int r = 0; r < 8; ++r) {
                    int e = r * 64 + lane;
                    bool up    = ((e & k) == 0);
                    bool isLow = ((lane & j) == 0);
                    unsigned long long va = key[r];
                    unsigned long long vb = __shfl_xor(va, j, 64);
                    bool keepMax = (up == isLow);
                    key[r] = keepMax ? (va > vb ? va : vb) : (va < vb ? va : vb);
                }
            }
        }
    }
    __syncthreads();
#pragma unroll
    for (int r = 0; r < 8; ++r) cand[r * 64 + lane] = key[r];
    __syncthreads();
#pragma unroll
    for (int r = 0; r < 8; ++r) {
        int e = r * 64 + lane;
        if (e < C) cbox[e] = bptr[(int)(~(unsigned)cand[e])];
    }
    __syncthreads();

    int t = 0;
    unsigned long long k0 = cand[0];
    float4 cb = cbox[0];
    while (t < C) {
        unsigned long long nk = 0ull;
        float4 nb = cb;
        if (t + 1 < C) { nk = cand[t + 1]; nb = cbox[t + 1]; }
        float sc = __uint_as_float((unsigned)(k0 >> 32));
        float ca = (cb.z - cb.x) * (cb.w - cb.y);
        bool over = false;
        if (lane < acc) {
            float tlx = fmaxf(rx1, cb.x);
            float tly = fmaxf(ry1, cb.y);
            float brx = fminf(rx2, cb.z);
            float bry = fminf(ry2, cb.w);
            float iw  = fmaxf(brx - tlx, 0.0f);
            float ih  = fmaxf(bry - tly, 0.0f);
            float inter = iw * ih;
            float iou = inter / (rar + ca - inter);
            over = iou > 0.5f;
        }
        if (!__any(over)) {
            if (lane == acc) { rx1 = cb.x; ry1 = cb.y; rx2 = cb.z; ry2 = cb.w; rar = ca; }
            if (lane == 0) {
                float* o = optr + (size_t)kout * 5;
                o[0] = sc; o[1] = cb.x; o[2] = cb.y; o[3] = cb.z; o[4] = cb.w;
            }
            acc++; kout++;
            if (acc == TOPK) break;
        }
        ++t; k0 = nk; cb = nb;
    }
}

__global__ __launch_bounds__(64, 4) void nms_fallback(const float* __restrict__ conf,
                                                      const float4* __restrict__ boxes,
                                                      float* __restrict__ out) {
    __shared__ int hist[NBINS];
    __shared__ unsigned long long cand[CAP];
    __shared__ float4 cbox[CAP];
    __shared__ int s_cnt;

    const int c    = blockIdx.x;
    const int b    = blockIdx.y;
    const int lane = threadIdx.x;

    const float4* bptr = boxes + (size_t)b * A_N;
    const float*  cptr = conf + (size_t)b * A_N * C_N + c;
    float* optr = out + (size_t)(b * C_N + c) * TOPK * 5;

    for (int i = lane; i < NBINS; i += 64) hist[i] = 0;
    __syncthreads();
    for (int i = 0; i < A_N / 256; ++i) {
        int a0 = 4 * (lane + 64 * i);
#pragma unroll
        for (int q = 0; q < 4; ++q) {
            float x = cptr[(size_t)(a0 + q) * C_N];
            float s = 1.0f / (1.0f + expf(-x));
            if (s > 0.3f) {
                unsigned u = __float_as_uint(s);
                int bin = (int)(u >> 16) - (int)BIN_BASE;
                bin = bin < 0 ? 0 : (bin > NBINS - 1 ? NBINS - 1 : bin);
                atomicAdd(&hist[bin], 1);
            }
        }
    }
    __syncthreads();

    float rx1 = 0.f, ry1 = 0.f, rx2 = 0.f, ry2 = 0.f, rar = 0.f;
    int acc = 0, kout = 0;
    int bin_hi = NBINS;
    for (;;) {
        int lo = bin_hi, tot = 0;
        while (lo > 0) {
            int cnt = hist[lo - 1];
            if (tot + cnt > CAP) { if (tot == 0) { lo--; } break; }
            tot += cnt; lo--;
        }
        const int bin_lo = lo;
        if (bin_lo == bin_hi) break;
        if (lane == 0) s_cnt = 0;
        __syncthreads();
        for (int i = 0; i < A_N / 256; ++i) {
            int a0 = 4 * (lane + 64 * i);
#pragma unroll
            for (int q = 0; q < 4; ++q) {
                float x = cptr[(size_t)(a0 + q) * C_N];
                float s = 1.0f / (1.0f + expf(-x));
                if (s > 0.3f) {
                    unsigned u = __float_as_uint(s);
                    int bin = (int)(u >> 16) - (int)BIN_BASE;
                    bin = bin < 0 ? 0 : (bin > NBINS - 1 ? NBINS - 1 : bin);
                    if (bin >= bin_lo && bin < bin_hi) {
                        int slot = atomicAdd(&s_cnt, 1);
                        if (slot < CAP)
                            cand[slot] = ((unsigned long long)u << 32) | (unsigned)(~(unsigned)(a0 + q));
                    }
                }
            }
        }
        __syncthreads();
        int C = s_cnt; if (C > CAP) C = CAP;
        if (C > 0)
            sort_gather_scan64(cand, cbox, C, lane, bptr, optr,
                               rx1, ry1, rx2, ry2, rar, acc, kout);
        if (acc == TOPK) break;
        bin_hi = bin_lo;
    }
    {
        float* o  = optr + (size_t)kout * 5;
        int   rem = (TOPK - kout) * 5;
        for (int i = lane; i < rem; i += 64) o[i] = 0.0f;
    }
}

extern "C" void kernel_launch(void* const* d_in, const int* in_sizes, int n_in,
                              void* d_out, int out_size, void* d_ws, size_t ws_size,
                              hipStream_t stream) {
    const float* loc     = (const float*)d_in[0];   // [B, A, 4]
    const float* conf    = (const float*)d_in[1];   // [B, A, C]
    const float* anchors = (const float*)d_in[2];   // [A, 4]
    float* out = (float*)d_out;                     // [B, C, TOPK, 5]

    const size_t boxes_bytes  = (size_t)B_N * A_N * sizeof(float4);          // 4 MB
    const size_t scores_bytes = (size_t)B_N * C_N * A_N * sizeof(float);     // 85 MB

    float4* boxes = (float4*)d_ws;

    decode_kernel<<<(B_N * A_N) / DNT, DNT, 0, stream>>>(
        (const float4*)loc, (const float4*)anchors, boxes);

    if (ws_size >= boxes_bytes + scores_bytes) {
        float* scoresT = (float*)((char*)d_ws + boxes_bytes);
        sigT_kernel<<<dim3(A_N / TA, B_N), TNT, 0, stream>>>(conf, scoresT);
        select_nms_kernel<<<dim3(B_N * C_N), SNT, 0, stream>>>(scoresT, boxes, out);
    } else {
        // fallback: strided conf reads, in-wave histogram (proven semantics)
        nms_fallback<<<dim3(C_N, B_N), 64, 0, stream>>>(conf, boxes, out);
    }
}